// Round 1
// baseline (145.846 us; speedup 1.0000x reference)
//
#include <hip/hip_runtime.h>
#include <cstdint>

#define B_ 2
#define H_ 16
#define S_ 2048
#define DK_ 64
#define BH_ (B_*H_)
#define NQT 32    // 64-row q tiles

typedef __attribute__((ext_vector_type(8))) short short8;
typedef __attribute__((ext_vector_type(4))) short short4v;
typedef __attribute__((ext_vector_type(4))) float floatx4;

__device__ inline unsigned short f2bf(float f) {
  union { float f; unsigned u; } v; v.f = f;
  unsigned u = v.u;
  unsigned r = u + 0x7fffu + ((u >> 16) & 1u);   // RNE
  return (unsigned short)(r >> 16);
}

__device__ inline floatx4 mfma16(short4v a, short4v b, floatx4 c) {
#if __has_builtin(__builtin_amdgcn_mfma_f32_16x16x16bf16_1k)
  return __builtin_amdgcn_mfma_f32_16x16x16bf16_1k(a, b, c, 0, 0, 0);
#else
  asm("v_mfma_f32_16x16x16_bf16 %0, %1, %2, %0" : "+v"(c) : "v"(a), "v"(b));
  return c;
#endif
}

__device__ inline short4v u2s4(unsigned a, unsigned b) {
  union { unsigned u[2]; short4v s; } v;
  v.u[0] = a; v.u[1] = b;
  return v.s;
}

// -------- prologue: K -> bf16 rows; V -> bf16 transposed [bh][d][s-permuted] --------
// V^T s-permutation within each 128-block: pos = 32*t2 + 8*q + 4*h + j for
// s = 32*t2 + 16*h + 4*q + j  -> PV A-frags become single b128 reads (2 slices/read).
// Note: permutation is contained within 32-s blocks, so 64-s kv tiles are contiguous.
__global__ __launch_bounds__(256) void conv_kv(const float* __restrict__ K,
                                               const float* __restrict__ V,
                                               unsigned short* __restrict__ Kb,
                                               unsigned short* __restrict__ Vb) {
  __shared__ __align__(16) unsigned short t[64 * 80];
  const int bh = blockIdx.y, s0 = blockIdx.x * 64;
  const int row = threadIdx.x >> 2, cp = threadIdx.x & 3;

  { // K: straight convert, coalesced
    const float* src = K + ((size_t)(bh * S_ + s0 + row)) * DK_ + cp * 16;
    unsigned short* dst = Kb + ((size_t)(bh * S_ + s0 + row)) * DK_ + cp * 16;
    #pragma unroll
    for (int h = 0; h < 2; ++h) {
      float4 a = *(const float4*)(src + h * 8);
      float4 b = *(const float4*)(src + h * 8 + 4);
      uint4 st;
      st.x = (unsigned)f2bf(a.x) | ((unsigned)f2bf(a.y) << 16);
      st.y = (unsigned)f2bf(a.z) | ((unsigned)f2bf(a.w) << 16);
      st.z = (unsigned)f2bf(b.x) | ((unsigned)f2bf(b.y) << 16);
      st.w = (unsigned)f2bf(b.z) | ((unsigned)f2bf(b.w) << 16);
      *(uint4*)(dst + h * 8) = st;
    }
  }
  { // V: transpose via LDS, then permuted store
    const float* src = V + ((size_t)(bh * S_ + s0 + row)) * DK_ + cp * 16;
    #pragma unroll
    for (int j4 = 0; j4 < 4; ++j4) {
      float4 a = *(const float4*)(src + j4 * 4);
      int c = cp * 16 + j4 * 4;
      t[(c + 0) * 80 + row] = f2bf(a.x);
      t[(c + 1) * 80 + row] = f2bf(a.y);
      t[(c + 2) * 80 + row] = f2bf(a.z);
      t[(c + 3) * 80 + row] = f2bf(a.w);
    }
    __syncthreads();
    // this thread owns s-range [s0+cp*16, +16): t2,h fixed; 4 runs of 4 (q=0..3)
    const int base128 = s0 & ~127;
    const int t2 = 2 * ((s0 >> 6) & 1) + (cp >> 1);
    const int h  = cp & 1;
    unsigned short* dst = Vb + ((size_t)(bh * DK_ + row)) * S_ + base128 + t2 * 32 + h * 4;
    #pragma unroll
    for (int q = 0; q < 4; ++q)
      *(uint2*)(dst + q * 8) = *(const uint2*)&t[row * 80 + cp * 16 + q * 4];
  }
}

// -------- flash attention: S^T formulation, occupancy-restructured ----------------
// 64-s kv tiles (LDS 32 KB dbuf -> 4 blocks/CU), 1024 blocks (one 64-row q-tile
// each, dynamic refill balances the causal triangle), each wave owns a private
// 16-q-row strip (no cross-wave epilogue reduction, 16 acc VGPRs).
__global__ __launch_bounds__(256, 4)
void fa_kernel(const float* __restrict__ Q, const unsigned short* __restrict__ Kb,
               const unsigned short* __restrict__ Vb, float* __restrict__ Out) {
  // Kt: 64 s-rows x 64 d (8 chunks/row, swizzle p=c^(row&7))
  // Vt: 64 d-rows x 64 s-permuted (8 chunks/row, swizzle p=c^(row&7))
  __shared__ __align__(16) unsigned short Kt[2][4096];
  __shared__ __align__(16) unsigned short Vt[2][4096];

  const int tid  = threadIdx.x;
  const int wave = tid >> 6;
  const int lane = tid & 63;
  const int quad = lane >> 4;
  const int l16  = lane & 15;
  const int wq   = wave;            // 16-q-row strip within the 64-row tile

  // XCD-aware decode: blocks with id%8==x -> XCD x sees bh in {x, x+8, x+16, x+24}
  // => 4 bh * 512 KB of K+V bf16 = 2 MB, fits the 4 MB per-XCD L2.
  const int id = blockIdx.x;
  const int bh = (id & 7) | (((id >> 3) & 3) << 3);
  const int qt = id >> 5;           // 0..31
  const int nkv = qt + 1;           // number of 64-s kv tiles (causal)

  const float SCL = 0.125f * 1.44269504088896340736f;  // 1/sqrt(64)*log2(e), folded into Q

  // ---- Q fragment, B-operand of S^T=K*Q^T: lane n=q=l16, k=d=quad*8+j (+32ks)
  short8 qf[2];
  {
    const float* p = Q + ((size_t)bh * S_ + qt * 64 + wq * 16 + l16) * DK_ + quad * 8;
    #pragma unroll
    for (int ks = 0; ks < 2; ++ks) {
      float4 x = *(const float4*)(p + ks * 32);
      float4 y = *(const float4*)(p + ks * 32 + 4);
      short8 t;
      t[0]=(short)f2bf(x.x*SCL); t[1]=(short)f2bf(x.y*SCL); t[2]=(short)f2bf(x.z*SCL); t[3]=(short)f2bf(x.w*SCL);
      t[4]=(short)f2bf(y.x*SCL); t[5]=(short)f2bf(y.y*SCL); t[6]=(short)f2bf(y.z*SCL); t[7]=(short)f2bf(y.w*SCL);
      qf[ks] = t;
    }
  }

  floatx4 Ot[4];                    // O^T partials per 16-d block
  float ls = 0.f;
  #pragma unroll
  for (int d = 0; d < 4; ++d) Ot[d] = (floatx4){0,0,0,0};

  auto stage = [&](int buf, int kv) {
    #pragma unroll
    for (int rd = 0; rd < 2; ++rd) {
      const int cid = rd * 256 + wave * 64 + lane;
      const int row = cid >> 3;                 // K: s-row / V: d-row (both 64x8 chunks)
      const int c   = (cid & 7) ^ (row & 7);    // store swizzle
      { // K tile
        const unsigned short* g = Kb + (((size_t)bh * S_ + kv * 64 + row) << 6) + (c << 3);
        __builtin_amdgcn_global_load_lds(
            (const __attribute__((address_space(1))) void*)g,
            (__attribute__((address_space(3))) void*)&Kt[buf][(rd * 4 + wave) * 512], 16, 0, 0);
      }
      { // V tile (positions pre-permuted in Vb; 64-s tile is contiguous)
        const unsigned short* g = Vb + (((size_t)bh * DK_ + row) << 11) + kv * 64 + (c << 3);
        __builtin_amdgcn_global_load_lds(
            (const __attribute__((address_space(1))) void*)g,
            (__attribute__((address_space(3))) void*)&Vt[buf][(rd * 4 + wave) * 512], 16, 0, 0);
      }
    }
  };

  auto computeT = [&](int cur, bool domask) {
    unsigned pk[4][2];   // [nt][pair] packed bf16x2 of exp'd scores
    #pragma unroll
    for (int nt = 0; nt < 4; ++nt) {
      if (domask && nt > wq) continue;          // fully above diagonal: skip (uniform)
      const int row = nt * 16 + l16;            // s-row in Kt
      floatx4 s0 = (floatx4){0,0,0,0};
      #pragma unroll
      for (int ks = 0; ks < 2; ++ks) {
        const int p = (ks * 4 + quad) ^ (l16 & 7);
        const short8 ak = *(const short8*)&Kt[cur][row * 64 + p * 8];
        s0 = __builtin_amdgcn_mfma_f32_16x16x32_bf16(ak, qf[ks], s0, 0, 0, 0);
      }
      if (domask && nt == wq) {   // S^T: lane holds q=l16, s=nt*16+quad*4+r
        #pragma unroll
        for (int r = 0; r < 4; ++r)
          if (quad * 4 + r > l16) s0[r] = -INFINITY;
      }
      float e0 = __builtin_amdgcn_exp2f(s0[0]);
      float e1 = __builtin_amdgcn_exp2f(s0[1]);
      float e2 = __builtin_amdgcn_exp2f(s0[2]);
      float e3 = __builtin_amdgcn_exp2f(s0[3]);
      ls += (e0 + e1) + (e2 + e3);
      // pack to bf16 pairs (round-half-up via +0x8000, byte-select hi16)
      pk[nt][0] = __builtin_amdgcn_perm(__float_as_uint(e1) + 0x8000u,
                                        __float_as_uint(e0) + 0x8000u, 0x07060302u);
      pk[nt][1] = __builtin_amdgcn_perm(__float_as_uint(e3) + 0x8000u,
                                        __float_as_uint(e2) + 0x8000u, 0x07060302u);
    }
    // O^T += V^T * P^T : P fed straight from registers (16x16x16 B-layout == C-layout)
    __builtin_amdgcn_s_setprio(1);
    #pragma unroll
    for (int dblk = 0; dblk < 4; ++dblk) {
      const int row = dblk * 16 + l16;          // d-row in Vt
      #pragma unroll
      for (int tt = 0; tt < 2; ++tt) {
        if (domask && 2 * tt > wq) continue;    // both 16-s slices masked out
        const int p = (tt * 4 + quad) ^ (l16 & 7);
        const short8 v8 = *(const short8*)&Vt[cur][row * 64 + p * 8];
        const short4v vlo = __builtin_shufflevector(v8, v8, 0, 1, 2, 3);  // slice 2tt
        const short4v vhi = __builtin_shufflevector(v8, v8, 4, 5, 6, 7);  // slice 2tt+1
        Ot[dblk] = mfma16(vlo, u2s4(pk[2*tt  ][0], pk[2*tt  ][1]), Ot[dblk]);
        if (!(domask && 2 * tt + 1 > wq))
          Ot[dblk] = mfma16(vhi, u2s4(pk[2*tt+1][0], pk[2*tt+1][1]), Ot[dblk]);
      }
    }
    __builtin_amdgcn_s_setprio(0);
  };

  // ---- main loop: 1 barrier/iter, dbuf prefetch in flight across the compute;
  //      masked (diagonal) tile peeled so the hot loop has no mask branches.
  stage(0, 0);
  __syncthreads();
  int kv = 0;
  for (; kv < nkv - 1; ++kv) {
    const int cur = kv & 1;
    stage(cur ^ 1, kv + 1);
    computeT(cur, false);
    __syncthreads();
  }
  computeT(kv & 1, true);

  // ---- epilogue: reduce l over quads; each wave owns its 16 q-rows outright
  ls += __shfl_xor(ls, 16);
  ls += __shfl_xor(ls, 32);
  const float inv = 1.0f / ls;
  float* og = Out + ((size_t)bh * S_ + qt * 64 + wq * 16 + l16) * DK_;
  #pragma unroll
  for (int dblk = 0; dblk < 4; ++dblk) {
    floatx4 tot = Ot[dblk] * inv;               // C row = quad*4+r -> d = dblk*16+quad*4+r
    *(floatx4*)(og + dblk * 16 + quad * 4) = tot;
  }
}

extern "C" void kernel_launch(void* const* d_in, const int* in_sizes, int n_in,
                              void* d_out, int out_size, void* d_ws, size_t ws_size,
                              hipStream_t stream) {
  const float* Q = (const float*)d_in[0];
  const float* K = (const float*)d_in[1];
  const float* V = (const float*)d_in[2];
  // d_in[3] = d_k (=64), d_in[4] = causal tril mask (applied analytically)
  float* Out = (float*)d_out;
  unsigned short* Kb = (unsigned short*)d_ws;                    // 8.4 MB
  unsigned short* Vb = Kb + (size_t)BH_ * S_ * DK_;              // 8.4 MB
  conv_kv<<<dim3(S_ / 64, BH_), 256, 0, stream>>>(K, V, Kb, Vb);
  fa_kernel<<<dim3(NQT * BH_), 256, 0, stream>>>(Q, Kb, Vb, Out);
}

// Round 2
// 142.698 us; speedup vs baseline: 1.0221x; 1.0221x over previous
//
#include <hip/hip_runtime.h>
#include <cstdint>

#define B_ 2
#define H_ 16
#define S_ 2048
#define DK_ 64
#define BH_ (B_*H_)
#define NQT 32    // 64-row q tiles

typedef __attribute__((ext_vector_type(8))) short short8;
typedef __attribute__((ext_vector_type(4))) short short4v;
typedef __attribute__((ext_vector_type(4))) float floatx4;

__device__ inline unsigned short f2bf(float f) {
  union { float f; unsigned u; } v; v.f = f;
  unsigned u = v.u;
  unsigned r = u + 0x7fffu + ((u >> 16) & 1u);   // RNE
  return (unsigned short)(r >> 16);
}

__device__ inline floatx4 mfma16(short4v a, short4v b, floatx4 c) {
#if __has_builtin(__builtin_amdgcn_mfma_f32_16x16x16bf16_1k)
  return __builtin_amdgcn_mfma_f32_16x16x16bf16_1k(a, b, c, 0, 0, 0);
#else
  asm("v_mfma_f32_16x16x16_bf16 %0, %1, %2, %0" : "+v"(c) : "v"(a), "v"(b));
  return c;
#endif
}

__device__ inline short4v u2s4(unsigned a, unsigned b) {
  union { unsigned u[2]; short4v s; } v;
  v.u[0] = a; v.u[1] = b;
  return v.s;
}

// -------- prologue: K -> bf16 rows; V -> bf16 transposed [bh][d][s-permuted] --------
// V^T s-permutation within each 128-block: pos = 32*t2 + 8*q + 4*h + j for
// s = 32*t2 + 16*h + 4*q + j  -> PV A-frags become single b128 reads (2 slices/read).
// Note: permutation is contained within 32-s blocks, so 64-s kv tiles are contiguous.
__global__ __launch_bounds__(256) void conv_kv(const float* __restrict__ K,
                                               const float* __restrict__ V,
                                               unsigned short* __restrict__ Kb,
                                               unsigned short* __restrict__ Vb) {
  __shared__ __align__(16) unsigned short t[64 * 80];
  const int bh = blockIdx.y, s0 = blockIdx.x * 64;
  const int row = threadIdx.x >> 2, cp = threadIdx.x & 3;

  { // K: straight convert, coalesced
    const float* src = K + ((size_t)(bh * S_ + s0 + row)) * DK_ + cp * 16;
    unsigned short* dst = Kb + ((size_t)(bh * S_ + s0 + row)) * DK_ + cp * 16;
    #pragma unroll
    for (int h = 0; h < 2; ++h) {
      float4 a = *(const float4*)(src + h * 8);
      float4 b = *(const float4*)(src + h * 8 + 4);
      uint4 st;
      st.x = (unsigned)f2bf(a.x) | ((unsigned)f2bf(a.y) << 16);
      st.y = (unsigned)f2bf(a.z) | ((unsigned)f2bf(a.w) << 16);
      st.z = (unsigned)f2bf(b.x) | ((unsigned)f2bf(b.y) << 16);
      st.w = (unsigned)f2bf(b.z) | ((unsigned)f2bf(b.w) << 16);
      *(uint4*)(dst + h * 8) = st;
    }
  }
  { // V: transpose via LDS, then permuted store
    const float* src = V + ((size_t)(bh * S_ + s0 + row)) * DK_ + cp * 16;
    #pragma unroll
    for (int j4 = 0; j4 < 4; ++j4) {
      float4 a = *(const float4*)(src + j4 * 4);
      int c = cp * 16 + j4 * 4;
      t[(c + 0) * 80 + row] = f2bf(a.x);
      t[(c + 1) * 80 + row] = f2bf(a.y);
      t[(c + 2) * 80 + row] = f2bf(a.z);
      t[(c + 3) * 80 + row] = f2bf(a.w);
    }
    __syncthreads();
    // this thread owns s-range [s0+cp*16, +16): t2,h fixed; 4 runs of 4 (q=0..3)
    const int base128 = s0 & ~127;
    const int t2 = 2 * ((s0 >> 6) & 1) + (cp >> 1);
    const int h  = cp & 1;
    unsigned short* dst = Vb + ((size_t)(bh * DK_ + row)) * S_ + base128 + t2 * 32 + h * 4;
    #pragma unroll
    for (int q = 0; q < 4; ++q)
      *(uint2*)(dst + q * 8) = *(const uint2*)&t[row * 80 + cp * 16 + q * 4];
  }
}

// -------- flash attention: S^T formulation, ring-3 counted-vmcnt pipeline --------
// 64-s kv tiles, ring of 3 LDS buffers (48 KB -> 3 blocks/CU), prefetch distance 2,
// ONE raw s_barrier per iteration with counted vmcnt(4) (never a full drain in the
// steady state). Heaviest q-tiles launch first (LPT). Each wave owns a private
// 16-q-row strip; PV uses split accumulators (8 dep-chains of 2 instead of 4 of 4).
__global__ __launch_bounds__(256, 3)
void fa_kernel(const float* __restrict__ Q, const unsigned short* __restrict__ Kb,
               const unsigned short* __restrict__ Vb, float* __restrict__ Out) {
  // Kt: 64 s-rows x 64 d (8 chunks/row, swizzle p=c^(row&7))
  // Vt: 64 d-rows x 64 s-permuted (8 chunks/row, swizzle p=c^(row&7))
  __shared__ __align__(16) unsigned short Kt[3][4096];
  __shared__ __align__(16) unsigned short Vt[3][4096];

  const int tid  = threadIdx.x;
  const int wave = tid >> 6;
  const int lane = tid & 63;
  const int quad = lane >> 4;
  const int l16  = lane & 15;
  const int wq   = wave;            // 16-q-row strip within the 64-row tile

  // XCD-aware decode: blocks with id%8==x -> XCD x sees bh in {x, x+8, x+16, x+24}
  // => 4 bh * 512 KB of K+V bf16 = 2 MB, fits the 4 MB per-XCD L2.
  // LPT: qt descending in dispatch order so 32-iteration blocks start first.
  const int id = blockIdx.x;
  const int bh = (id & 7) | (((id >> 3) & 3) << 3);
  const int qt = NQT - 1 - (id >> 5);   // 31..0
  const int nkv = qt + 1;               // number of 64-s kv tiles (causal)

  const float SCL = 0.125f * 1.44269504088896340736f;  // 1/sqrt(64)*log2(e), folded into Q

  // ---- Q fragment, B-operand of S^T=K*Q^T: lane n=q=l16, k=d=quad*8+j (+32ks)
  short8 qf[2];
  {
    const float* p = Q + ((size_t)bh * S_ + qt * 64 + wq * 16 + l16) * DK_ + quad * 8;
    #pragma unroll
    for (int ks = 0; ks < 2; ++ks) {
      float4 x = *(const float4*)(p + ks * 32);
      float4 y = *(const float4*)(p + ks * 32 + 4);
      short8 t;
      t[0]=(short)f2bf(x.x*SCL); t[1]=(short)f2bf(x.y*SCL); t[2]=(short)f2bf(x.z*SCL); t[3]=(short)f2bf(x.w*SCL);
      t[4]=(short)f2bf(y.x*SCL); t[5]=(short)f2bf(y.y*SCL); t[6]=(short)f2bf(y.z*SCL); t[7]=(short)f2bf(y.w*SCL);
      qf[ks] = t;
    }
  }

  floatx4 Ot[4], Ou[4];             // split O^T accumulators per 16-d block
  float ls = 0.f;
  #pragma unroll
  for (int d = 0; d < 4; ++d) { Ot[d] = (floatx4){0,0,0,0}; Ou[d] = (floatx4){0,0,0,0}; }

  auto stage = [&](int buf, int kv) {    // 4 global_load_lds (1 KiB each) per wave
    #pragma unroll
    for (int rd = 0; rd < 2; ++rd) {
      const int cid = rd * 256 + wave * 64 + lane;
      const int row = cid >> 3;                 // K: s-row / V: d-row (both 64x8 chunks)
      const int c   = (cid & 7) ^ (row & 7);    // store swizzle
      { // K tile
        const unsigned short* g = Kb + (((size_t)bh * S_ + kv * 64 + row) << 6) + (c << 3);
        __builtin_amdgcn_global_load_lds(
            (const __attribute__((address_space(1))) void*)g,
            (__attribute__((address_space(3))) void*)&Kt[buf][(rd * 4 + wave) * 512], 16, 0, 0);
      }
      { // V tile (positions pre-permuted in Vb; 64-s tile is contiguous)
        const unsigned short* g = Vb + (((size_t)bh * DK_ + row) << 11) + kv * 64 + (c << 3);
        __builtin_amdgcn_global_load_lds(
            (const __attribute__((address_space(1))) void*)g,
            (__attribute__((address_space(3))) void*)&Vt[buf][(rd * 4 + wave) * 512], 16, 0, 0);
      }
    }
  };

  auto computeT = [&](int cur, bool domask) {
    unsigned pk[4][2];   // [nt][pair] packed bf16x2 of exp'd scores
    #pragma unroll
    for (int nt = 0; nt < 4; ++nt) {
      if (domask && nt > wq) continue;          // fully above diagonal: skip (uniform)
      const int row = nt * 16 + l16;            // s-row in Kt
      floatx4 s0 = (floatx4){0,0,0,0};
      __builtin_amdgcn_s_setprio(1);
      #pragma unroll
      for (int ks = 0; ks < 2; ++ks) {
        const int p = (ks * 4 + quad) ^ (l16 & 7);
        const short8 ak = *(const short8*)&Kt[cur][row * 64 + p * 8];
        s0 = __builtin_amdgcn_mfma_f32_16x16x32_bf16(ak, qf[ks], s0, 0, 0, 0);
      }
      __builtin_amdgcn_s_setprio(0);
      if (domask && nt == wq) {   // S^T: lane holds q=l16, s=nt*16+quad*4+r
        #pragma unroll
        for (int r = 0; r < 4; ++r)
          if (quad * 4 + r > l16) s0[r] = -INFINITY;
      }
      float e0 = __builtin_amdgcn_exp2f(s0[0]);
      float e1 = __builtin_amdgcn_exp2f(s0[1]);
      float e2 = __builtin_amdgcn_exp2f(s0[2]);
      float e3 = __builtin_amdgcn_exp2f(s0[3]);
      ls += (e0 + e1) + (e2 + e3);
      // pack to bf16 pairs (round-half-up via +0x8000, byte-select hi16)
      pk[nt][0] = __builtin_amdgcn_perm(__float_as_uint(e1) + 0x8000u,
                                        __float_as_uint(e0) + 0x8000u, 0x07060302u);
      pk[nt][1] = __builtin_amdgcn_perm(__float_as_uint(e3) + 0x8000u,
                                        __float_as_uint(e2) + 0x8000u, 0x07060302u);
    }
    // O^T += V^T * P^T : P fed straight from registers (16x16x16 B-layout == C-layout)
    // vlo products -> Ot, vhi -> Ou: 8 independent 2-deep accumulate chains.
    __builtin_amdgcn_s_setprio(1);
    #pragma unroll
    for (int dblk = 0; dblk < 4; ++dblk) {
      const int row = dblk * 16 + l16;          // d-row in Vt
      #pragma unroll
      for (int tt = 0; tt < 2; ++tt) {
        if (domask && 2 * tt > wq) continue;    // both 16-s slices masked out
        const int p = (tt * 4 + quad) ^ (l16 & 7);
        const short8 v8 = *(const short8*)&Vt[cur][row * 64 + p * 8];
        const short4v vlo = __builtin_shufflevector(v8, v8, 0, 1, 2, 3);  // slice 2tt
        const short4v vhi = __builtin_shufflevector(v8, v8, 4, 5, 6, 7);  // slice 2tt+1
        Ot[dblk] = mfma16(vlo, u2s4(pk[2*tt  ][0], pk[2*tt  ][1]), Ot[dblk]);
        if (!(domask && 2 * tt + 1 > wq))
          Ou[dblk] = mfma16(vhi, u2s4(pk[2*tt+1][0], pk[2*tt+1][1]), Ou[dblk]);
      }
    }
    __builtin_amdgcn_s_setprio(0);
  };

  // ---- main loop: ring-3, prefetch distance 2, ONE raw barrier per iteration.
  // Wait accounting (4 loads per stage per wave, in-order vmcnt): at iter kv the
  // wave has stage kv (oldest 4) + stage kv+1 (newest 4) outstanding -> vmcnt(4)
  // keeps kv+1 in flight across the barrier. Tail iteration drains with vmcnt(0).
  // WAR safety: stage(kv+2) overwrites the slot last read in compute(kv-1); every
  // wave passed this iteration's barrier only after finishing compute(kv-1).
  stage(0, 0);
  if (nkv > 1) stage(1, 1);
  int cur = 0;
  for (int kv = 0; kv < nkv; ++kv) {
    if (kv + 1 < nkv) asm volatile("s_waitcnt vmcnt(4)" ::: "memory");
    else              asm volatile("s_waitcnt vmcnt(0)" ::: "memory");
    __builtin_amdgcn_s_barrier();
    if (kv + 2 < nkv) stage(cur == 0 ? 2 : cur - 1, kv + 2);   // slot (kv+2)%3
    computeT(cur, kv == nkv - 1);
    cur = (cur == 2) ? 0 : cur + 1;
  }

  // ---- epilogue: reduce l over quads; each wave owns its 16 q-rows outright
  ls += __shfl_xor(ls, 16);
  ls += __shfl_xor(ls, 32);
  const float inv = 1.0f / ls;
  float* og = Out + ((size_t)bh * S_ + qt * 64 + wq * 16 + l16) * DK_;
  #pragma unroll
  for (int dblk = 0; dblk < 4; ++dblk) {
    floatx4 tot = (Ot[dblk] + Ou[dblk]) * inv;  // C row = quad*4+r -> d = dblk*16+quad*4+r
    *(floatx4*)(og + dblk * 16 + quad * 4) = tot;
  }
}

extern "C" void kernel_launch(void* const* d_in, const int* in_sizes, int n_in,
                              void* d_out, int out_size, void* d_ws, size_t ws_size,
                              hipStream_t stream) {
  const float* Q = (const float*)d_in[0];
  const float* K = (const float*)d_in[1];
  const float* V = (const float*)d_in[2];
  // d_in[3] = d_k (=64), d_in[4] = causal tril mask (applied analytically)
  float* Out = (float*)d_out;
  unsigned short* Kb = (unsigned short*)d_ws;                    // 8.4 MB
  unsigned short* Vb = Kb + (size_t)BH_ * S_ * DK_;              // 8.4 MB
  conv_kv<<<dim3(S_ / 64, BH_), 256, 0, stream>>>(K, V, Kb, Vb);
  fa_kernel<<<dim3(NQT * BH_), 256, 0, stream>>>(Q, Kb, Vb, Out);
}